// Round 3
// baseline (1491.324 us; speedup 1.0000x reference)
//
#include <hip/hip_runtime.h>

#define NATOMS 20000
#define NEDGES 640000
#define HID 128
#define EDIM 64

__device__ __forceinline__ void fma4(float4& a, const float4 w, const float s) {
  a.x = fmaf(w.x, s, a.x);
  a.y = fmaf(w.y, s, a.y);
  a.z = fmaf(w.z, s, a.z);
  a.w = fmaf(w.w, s, a.w);
}

// ---------------- K1: m = relu([h_v[src], edge_attr] @ W_i); agg[dst] += m ----
#define K1K 192
#define ST1 68   // LDS row stride (floats), mult of 4 for float4 alignment

__global__ __launch_bounds__(256) void k1_msg_scatter(
    const float* __restrict__ h_v, const int* __restrict__ ei,
    const float* __restrict__ edge_attr, const float* __restrict__ W_i,
    float* __restrict__ agg)
{
  __shared__ float xt[K1K * ST1];          // 52.2 KB -> 3 blocks/CU
  const int t = threadIdx.x;
  const int ebase = blockIdx.x * 64;

  { // stage 64 edges x 192 floats, transposed xt[k][e]
    const int el = t & 63;
    const int part = t >> 6;               // 0..3
    const int ge = ebase + el;
    const int s = ei[ge];                  // src row (int32 on device!)
    const float4* hv4 = (const float4*)(h_v + (long long)s * HID);
    const float4* ea4 = (const float4*)(edge_attr + (long long)ge * EDIM);
    #pragma unroll
    for (int i = 0; i < 8; ++i) {          // c = part + i*4 in 0..31 -> h_v
      const int c = part + i * 4;
      const float4 v = hv4[c];
      const int k = c * 4;
      xt[(k + 0) * ST1 + el] = v.x;
      xt[(k + 1) * ST1 + el] = v.y;
      xt[(k + 2) * ST1 + el] = v.z;
      xt[(k + 3) * ST1 + el] = v.w;
    }
    #pragma unroll
    for (int i = 8; i < 12; ++i) {         // c in 32..47 -> edge_attr
      const int c = part + i * 4;
      const float4 v = ea4[c - 32];
      const int k = c * 4;
      xt[(k + 0) * ST1 + el] = v.x;
      xt[(k + 1) * ST1 + el] = v.y;
      xt[(k + 2) * ST1 + el] = v.z;
      xt[(k + 3) * ST1 + el] = v.w;
    }
  }
  __syncthreads();

  const int j4 = t & 31;                   // output quad: j = j4*4
  const int e0 = (t >> 5) * 8;             // 8 edges per thread
  float4 acc[8];
  #pragma unroll
  for (int i = 0; i < 8; ++i) acc[i] = make_float4(0.f, 0.f, 0.f, 0.f);

  const float4* W4 = (const float4*)W_i;   // W[k][j]: W4[k*32 + j4]
  #pragma unroll 4
  for (int k = 0; k < K1K; ++k) {
    const float4 w  = W4[k * 32 + j4];
    const float4 xa = *(const float4*)(xt + k * ST1 + e0);
    const float4 xb = *(const float4*)(xt + k * ST1 + e0 + 4);
    fma4(acc[0], w, xa.x); fma4(acc[1], w, xa.y);
    fma4(acc[2], w, xa.z); fma4(acc[3], w, xa.w);
    fma4(acc[4], w, xb.x); fma4(acc[5], w, xb.y);
    fma4(acc[6], w, xb.z); fma4(acc[7], w, xb.w);
  }

  const int* dstp = ei + NEDGES;
  #pragma unroll
  for (int i = 0; i < 8; ++i) {
    const int d = dstp[ebase + e0 + i];
    float* o = agg + (long long)d * HID + j4 * 4;
    atomicAdd(o + 0, fmaxf(acc[i].x, 0.f));
    atomicAdd(o + 1, fmaxf(acc[i].y, 0.f));
    atomicAdd(o + 2, fmaxf(acc[i].z, 0.f));
    atomicAdd(o + 3, fmaxf(acc[i].w, 0.f));
  }
}

// ---------------- K2: h_e_new = relu(h_e @ W_h + agg[src]) -------------------
#define ST2 68

__global__ __launch_bounds__(256) void k2_edge_update(
    const float* __restrict__ h_e, const int* __restrict__ ei,
    const float* __restrict__ W_h, const float* __restrict__ agg,
    float* __restrict__ h_e_new)
{
  __shared__ float xt[HID * ST2];          // 34.8 KB -> 4 blocks/CU
  const int t = threadIdx.x;
  const int ebase = blockIdx.x * 64;

  { // stage 64 edges x 128 floats, transposed
    const int el = t & 63;
    const int part = t >> 6;               // 0..3
    const long long ge = ebase + el;
    const float4* he4 = (const float4*)(h_e + ge * HID);
    #pragma unroll
    for (int i = 0; i < 8; ++i) {
      const int c = part + i * 4;          // 0..31
      const float4 v = he4[c];
      const int k = c * 4;
      xt[(k + 0) * ST2 + el] = v.x;
      xt[(k + 1) * ST2 + el] = v.y;
      xt[(k + 2) * ST2 + el] = v.z;
      xt[(k + 3) * ST2 + el] = v.w;
    }
  }
  __syncthreads();

  const int j4 = t & 31;
  const int e0 = (t >> 5) * 8;
  float4 acc[8];
  #pragma unroll
  for (int i = 0; i < 8; ++i) acc[i] = make_float4(0.f, 0.f, 0.f, 0.f);

  const float4* W4 = (const float4*)W_h;
  #pragma unroll 4
  for (int k = 0; k < HID; ++k) {
    const float4 w  = W4[k * 32 + j4];
    const float4 xa = *(const float4*)(xt + k * ST2 + e0);
    const float4 xb = *(const float4*)(xt + k * ST2 + e0 + 4);
    fma4(acc[0], w, xa.x); fma4(acc[1], w, xa.y);
    fma4(acc[2], w, xa.z); fma4(acc[3], w, xa.w);
    fma4(acc[4], w, xb.x); fma4(acc[5], w, xb.y);
    fma4(acc[6], w, xb.z); fma4(acc[7], w, xb.w);
  }

  #pragma unroll
  for (int i = 0; i < 8; ++i) {
    const int ge = ebase + e0 + i;
    const int s = ei[ge];                  // src (int32)
    const float4 a = *(const float4*)(agg + (long long)s * HID + j4 * 4);
    float4 r;
    r.x = fmaxf(acc[i].x + a.x, 0.f);
    r.y = fmaxf(acc[i].y + a.y, 0.f);
    r.z = fmaxf(acc[i].z + a.z, 0.f);
    r.w = fmaxf(acc[i].w + a.w, 0.f);
    *(float4*)(h_e_new + (long long)ge * HID + j4 * 4) = r;
  }
}

// ---------------- K3: h_v_new = relu([h_v, agg] @ W_o + b_o) -----------------
// NOTE: h_v_new aliases agg (in-place). Safe: each block stages its own 32 rows
// of agg into LDS before __syncthreads, then overwrites exactly those rows.
#define ST3 36

__global__ __launch_bounds__(256) void k3_atom_update(
    const float* __restrict__ h_v, const float* __restrict__ agg,
    const float* __restrict__ W_o, const float* __restrict__ b_o,
    float* __restrict__ h_v_new)
{
  __shared__ float xt[256 * ST3];          // 36.9 KB
  const int t = threadIdx.x;
  const int rbase = blockIdx.x * 32;

  { // stage 32 rows x 256 floats, transposed
    const int rl = t & 31;
    const int part = t >> 5;               // 0..7
    const int gr = rbase + rl;
    const bool ok = gr < NATOMS;
    const float4* hv4 = (const float4*)(h_v + (long long)gr * HID);
    const float4* ag4 = (const float4*)(agg + (long long)gr * HID);
    #pragma unroll
    for (int i = 0; i < 4; ++i) {          // c = part + i*8 in 0..31 -> h_v
      const int c = part + i * 8;
      float4 v = make_float4(0.f, 0.f, 0.f, 0.f);
      if (ok) v = hv4[c];
      const int k = c * 4;
      xt[(k + 0) * ST3 + rl] = v.x;
      xt[(k + 1) * ST3 + rl] = v.y;
      xt[(k + 2) * ST3 + rl] = v.z;
      xt[(k + 3) * ST3 + rl] = v.w;
    }
    #pragma unroll
    for (int i = 4; i < 8; ++i) {          // c in 32..63 -> agg
      const int c = part + i * 8;
      float4 v = make_float4(0.f, 0.f, 0.f, 0.f);
      if (ok) v = ag4[c - 32];
      const int k = c * 4;
      xt[(k + 0) * ST3 + rl] = v.x;
      xt[(k + 1) * ST3 + rl] = v.y;
      xt[(k + 2) * ST3 + rl] = v.z;
      xt[(k + 3) * ST3 + rl] = v.w;
    }
  }
  __syncthreads();

  const int j4 = t & 31;
  const int e0 = (t >> 5) * 4;             // 4 rows per thread
  float4 acc[4];
  #pragma unroll
  for (int i = 0; i < 4; ++i) acc[i] = make_float4(0.f, 0.f, 0.f, 0.f);

  const float4* W4 = (const float4*)W_o;
  #pragma unroll 4
  for (int k = 0; k < 256; ++k) {
    const float4 w  = W4[k * 32 + j4];
    const float4 xa = *(const float4*)(xt + k * ST3 + e0);
    fma4(acc[0], w, xa.x); fma4(acc[1], w, xa.y);
    fma4(acc[2], w, xa.z); fma4(acc[3], w, xa.w);
  }

  const float4 b = ((const float4*)b_o)[j4];
  #pragma unroll
  for (int i = 0; i < 4; ++i) {
    const int gr = rbase + e0 + i;
    if (gr < NATOMS) {
      float4 r;
      r.x = fmaxf(acc[i].x + b.x, 0.f);
      r.y = fmaxf(acc[i].y + b.y, 0.f);
      r.z = fmaxf(acc[i].z + b.z, 0.f);
      r.w = fmaxf(acc[i].w + b.w, 0.f);
      *(float4*)(h_v_new + (long long)gr * HID + j4 * 4) = r;
    }
  }
}

// -----------------------------------------------------------------------------
extern "C" void kernel_launch(void* const* d_in, const int* in_sizes, int n_in,
                              void* d_out, int out_size, void* d_ws, size_t ws_size,
                              hipStream_t stream) {
  const float* h_v       = (const float*)d_in[0];
  const int*   ei        = (const int*)d_in[1];             // [2, NEDGES] as int32 on device
  const float* edge_attr = (const float*)d_in[2];
  const float* h_e       = (const float*)d_in[3];
  const float* W_i       = (const float*)d_in[4];           // [192,128]
  const float* W_h       = (const float*)d_in[5];           // [128,128]
  const float* W_o       = (const float*)d_in[6];           // [256,128]
  const float* b_o       = (const float*)d_in[7];           // [128]

  float* out      = (float*)d_out;
  float* h_v_new  = out;                                    // [20000,128]
  float* h_e_new  = out + (size_t)NATOMS * HID;             // [640000,128]
  // agg aliases the h_v_new region of d_out (same shape). No d_ws dependence.
  float* agg      = h_v_new;

  hipMemsetAsync(agg, 0, (size_t)NATOMS * HID * sizeof(float), stream);

  k1_msg_scatter<<<NEDGES / 64, 256, 0, stream>>>(h_v, ei, edge_attr, W_i, agg);
  k2_edge_update<<<NEDGES / 64, 256, 0, stream>>>(h_e, ei, W_h, agg, h_e_new);
  k3_atom_update<<<(NATOMS + 31) / 32, 256, 0, stream>>>(h_v, agg, W_o, b_o, h_v_new);
}

// Round 4
// 517.727 us; speedup vs baseline: 2.8805x; 2.8805x over previous
//
#include <hip/hip_runtime.h>

#define NATOMS 20000
#define NEDGES 640000
#define HID 128
#define EDIM 64
#define NTILES (NEDGES / 64)   // 10000

typedef __attribute__((ext_vector_type(8))) short bf16x8;
typedef __attribute__((ext_vector_type(4))) float f32x4;

__device__ __forceinline__ unsigned short f2b(float f) {
  union { float f; unsigned u; } c; c.f = f;
  unsigned u = c.u + 0x7fff + ((c.u >> 16) & 1);   // RNE (finite data)
  return (unsigned short)(u >> 16);
}
__device__ __forceinline__ float b2f(unsigned short s) {
  union { unsigned u; float f; } c; c.u = ((unsigned)s) << 16;
  return c.f;
}

// pack 8 f32 -> 8 bf16 and write 16B to LDS
__device__ __forceinline__ void write8(unsigned short* p, float4 a, float4 b) {
  union { unsigned short u[8]; uint4 q; } pk;
  pk.u[0] = f2b(a.x); pk.u[1] = f2b(a.y); pk.u[2] = f2b(a.z); pk.u[3] = f2b(a.w);
  pk.u[4] = f2b(b.x); pk.u[5] = f2b(b.y); pk.u[6] = f2b(b.z); pk.u[7] = f2b(b.w);
  *(uint4*)p = pk.q;
}

// Per-wave W fragments: wave owns cols [wbase, wbase+32). W fp32 [K][128].
// b-frag lane l: B[k= ks*32 + (l>>4)*8 + j][ wbase + ni*16 + (l&15) ]
template <int KSTEPS>
__device__ __forceinline__ void load_w(const float* __restrict__ W, int wbase,
                                       int lane, bf16x8 B[KSTEPS][2]) {
  const int col0 = wbase + (lane & 15);
  const int krow0 = (lane >> 4) * 8;
  #pragma unroll
  for (int ks = 0; ks < KSTEPS; ++ks)
    #pragma unroll
    for (int ni = 0; ni < 2; ++ni) {
      const float* p = W + (long long)(ks * 32 + krow0) * HID + col0 + ni * 16;
      bf16x8 b;
      #pragma unroll
      for (int j = 0; j < 8; ++j) b[j] = (short)f2b(p[(long long)j * HID]);
      B[ks][ni] = b;
    }
}

// ---------------- CSR build --------------------------------------------------
__global__ __launch_bounds__(256) void k_hist(const int* __restrict__ dst,
                                              int* __restrict__ hist) {
  int e = blockIdx.x * 256 + threadIdx.x;
  if (e < NEDGES) atomicAdd(&hist[dst[e]], 1);
}

__global__ __launch_bounds__(256) void k_scan(const int* __restrict__ hist,
                                              int* __restrict__ rowptr,
                                              int* __restrict__ cursor) {
  __shared__ int part[256];
  const int t = threadIdx.x;
  const int CH = (NATOMS + 255) / 256;     // 79
  const int lo = t * CH, hi = min(lo + CH, NATOMS);
  int s = 0;
  for (int i = lo; i < hi; ++i) s += hist[i];
  part[t] = s; __syncthreads();
  for (int off = 1; off < 256; off <<= 1) {
    int v = (t >= off) ? part[t - off] : 0;
    __syncthreads();
    part[t] += v;
    __syncthreads();
  }
  int run = (t == 0) ? 0 : part[t - 1];
  for (int i = lo; i < hi; ++i) { rowptr[i] = run; cursor[i] = run; run += hist[i]; }
  if (t == 255) rowptr[NATOMS] = run;
}

__global__ __launch_bounds__(256) void k_fill(const int* __restrict__ dst,
                                              int* __restrict__ cursor,
                                              int* __restrict__ idx) {
  int e = blockIdx.x * 256 + threadIdx.x;
  if (e < NEDGES) {
    int p = atomicAdd(&cursor[dst[e]], 1);
    idx[p] = e;
  }
}

// ---------------- K1: m = relu([h_v[src]|edge_attr] @ W_i)  (bf16 MFMA) ------
#define A1_ST 200   // bf16 elems/row: mult of 8 -> 16B-aligned rows; 2-way banks

__global__ __launch_bounds__(256, 2) void k1_mfma(
    const float* __restrict__ h_v, const int* __restrict__ ei,
    const float* __restrict__ edge_attr, const float* __restrict__ W_i,
    unsigned short* __restrict__ m_out)
{
  __shared__ __align__(16) unsigned short A[64 * A1_ST];   // 25.6 KB
  const int t = threadIdx.x, lane = t & 63, w = t >> 6;

  bf16x8 B[6][2];
  load_w<6>(W_i, w * 32, lane, B);

  for (int tile = blockIdx.x; tile < NTILES; tile += gridDim.x) {
    const int ebase = tile * 64;
    { // stage A: wave w covers cols [w*48, w*48+48); lane = edge row
      const int el = lane;
      const int ge = ebase + el;
      const int s = ei[ge];
      const float* hv = h_v + (long long)s * HID;
      const float* ea = edge_attr + (long long)ge * EDIM;
      #pragma unroll
      for (int i = 0; i < 6; ++i) {
        const int c0 = w * 48 + i * 8;
        const float* src = (c0 < HID) ? (hv + c0) : (ea + (c0 - HID));
        float4 v0 = *(const float4*)(src);
        float4 v1 = *(const float4*)(src + 4);
        write8(&A[el * A1_ST + c0], v0, v1);
      }
    }
    __syncthreads();

    f32x4 acc[4][2];
    #pragma unroll
    for (int mi = 0; mi < 4; ++mi)
      #pragma unroll
      for (int ni = 0; ni < 2; ++ni) acc[mi][ni] = (f32x4){0.f, 0.f, 0.f, 0.f};

    #pragma unroll
    for (int ks = 0; ks < 6; ++ks) {
      const int kk = ks * 32 + (lane >> 4) * 8;
      bf16x8 a[4];
      #pragma unroll
      for (int mi = 0; mi < 4; ++mi)
        a[mi] = *(const bf16x8*)&A[(mi * 16 + (lane & 15)) * A1_ST + kk];
      #pragma unroll
      for (int mi = 0; mi < 4; ++mi) {
        acc[mi][0] = __builtin_amdgcn_mfma_f32_16x16x32_bf16(a[mi], B[ks][0], acc[mi][0], 0, 0, 0);
        acc[mi][1] = __builtin_amdgcn_mfma_f32_16x16x32_bf16(a[mi], B[ks][1], acc[mi][1], 0, 0, 0);
      }
    }

    { // epilogue: relu -> bf16 stores.  D: col=lane&15, row=(lane>>4)*4+reg
      const int colb = w * 32 + (lane & 15);
      const int rb = ebase + ((lane >> 4) << 2);
      #pragma unroll
      for (int mi = 0; mi < 4; ++mi)
        #pragma unroll
        for (int ni = 0; ni < 2; ++ni)
          #pragma unroll
          for (int r = 0; r < 4; ++r) {
            const int row = rb + mi * 16 + r;
            m_out[(long long)row * HID + colb + ni * 16] =
                f2b(fmaxf(acc[mi][ni][r], 0.f));
          }
    }
    __syncthreads();
  }
}

// ---------------- agg[a] = sum of m rows with dst == a -----------------------
__global__ __launch_bounds__(128) void k_agg(
    const unsigned short* __restrict__ m, const int* __restrict__ rowptr,
    const int* __restrict__ idx, float* __restrict__ agg)
{
  const int a = blockIdx.x, j = threadIdx.x;
  const int lo = rowptr[a], hi = rowptr[a + 1];
  float s = 0.f;
  int i = lo;
  for (; i + 1 < hi; i += 2) {
    const int e0 = idx[i], e1 = idx[i + 1];
    s += b2f(m[(long long)e0 * HID + j]);
    s += b2f(m[(long long)e1 * HID + j]);
  }
  if (i < hi) s += b2f(m[(long long)idx[i] * HID + j]);
  agg[(long long)a * HID + j] = s;
}

// ---------------- K2: h_e_new = relu(h_e @ W_h + agg[src])  (bf16 MFMA) ------
#define A2_ST 136   // mult of 8 -> aligned; 2-way banks

__global__ __launch_bounds__(256, 2) void k2_mfma(
    const float* __restrict__ h_e, const int* __restrict__ ei,
    const float* __restrict__ W_h, const float* __restrict__ agg,
    float* __restrict__ h_e_new)
{
  __shared__ __align__(16) unsigned short A[64 * A2_ST];   // 17.4 KB
  const int t = threadIdx.x, lane = t & 63, w = t >> 6;

  bf16x8 B[4][2];
  load_w<4>(W_h, w * 32, lane, B);

  for (int tile = blockIdx.x; tile < NTILES; tile += gridDim.x) {
    const int ebase = tile * 64;
    { // stage h_e rows (sequential)
      const int el = lane;
      const float* he = h_e + (long long)(ebase + el) * HID;
      #pragma unroll
      for (int i = 0; i < 4; ++i) {
        const int c0 = w * 32 + i * 8;
        float4 v0 = *(const float4*)(he + c0);
        float4 v1 = *(const float4*)(he + c0 + 4);
        write8(&A[el * A2_ST + c0], v0, v1);
      }
    }
    __syncthreads();

    f32x4 acc[4][2];
    #pragma unroll
    for (int mi = 0; mi < 4; ++mi)
      #pragma unroll
      for (int ni = 0; ni < 2; ++ni) acc[mi][ni] = (f32x4){0.f, 0.f, 0.f, 0.f};

    #pragma unroll
    for (int ks = 0; ks < 4; ++ks) {
      const int kk = ks * 32 + (lane >> 4) * 8;
      bf16x8 a[4];
      #pragma unroll
      for (int mi = 0; mi < 4; ++mi)
        a[mi] = *(const bf16x8*)&A[(mi * 16 + (lane & 15)) * A2_ST + kk];
      #pragma unroll
      for (int mi = 0; mi < 4; ++mi) {
        acc[mi][0] = __builtin_amdgcn_mfma_f32_16x16x32_bf16(a[mi], B[ks][0], acc[mi][0], 0, 0, 0);
        acc[mi][1] = __builtin_amdgcn_mfma_f32_16x16x32_bf16(a[mi], B[ks][1], acc[mi][1], 0, 0, 0);
      }
    }

    { // epilogue: + agg[src] gather, relu, f32 stores
      const int colb = w * 32 + (lane & 15);
      const int rb = ebase + ((lane >> 4) << 2);
      #pragma unroll
      for (int mi = 0; mi < 4; ++mi)
        #pragma unroll
        for (int r = 0; r < 4; ++r) {
          const int row = rb + mi * 16 + r;
          const int s = ei[row];                    // src
          const float* ag = agg + (long long)s * HID + colb;
          float* o = h_e_new + (long long)row * HID + colb;
          o[0]  = fmaxf(acc[mi][0][r] + ag[0], 0.f);
          o[16] = fmaxf(acc[mi][1][r] + ag[16], 0.f);
        }
    }
    __syncthreads();
  }
}

// ---------------- K3: h_v_new = relu([h_v, agg] @ W_o + b_o)  (fp32 VALU) ----
// h_v_new aliases agg (in-place); each block stages its 32 rows before sync.
__device__ __forceinline__ void fma4(float4& a, const float4 w, const float s) {
  a.x = fmaf(w.x, s, a.x);
  a.y = fmaf(w.y, s, a.y);
  a.z = fmaf(w.z, s, a.z);
  a.w = fmaf(w.w, s, a.w);
}
#define ST3 36

__global__ __launch_bounds__(256) void k3_atom_update(
    const float* __restrict__ h_v, const float* __restrict__ agg,
    const float* __restrict__ W_o, const float* __restrict__ b_o,
    float* __restrict__ h_v_new)
{
  __shared__ float xt[256 * ST3];
  const int t = threadIdx.x;
  const int rbase = blockIdx.x * 32;

  {
    const int rl = t & 31;
    const int part = t >> 5;
    const int gr = rbase + rl;
    const bool ok = gr < NATOMS;
    const float4* hv4 = (const float4*)(h_v + (long long)gr * HID);
    const float4* ag4 = (const float4*)(agg + (long long)gr * HID);
    #pragma unroll
    for (int i = 0; i < 4; ++i) {
      const int c = part + i * 8;
      float4 v = make_float4(0.f, 0.f, 0.f, 0.f);
      if (ok) v = hv4[c];
      const int k = c * 4;
      xt[(k + 0) * ST3 + rl] = v.x;
      xt[(k + 1) * ST3 + rl] = v.y;
      xt[(k + 2) * ST3 + rl] = v.z;
      xt[(k + 3) * ST3 + rl] = v.w;
    }
    #pragma unroll
    for (int i = 4; i < 8; ++i) {
      const int c = part + i * 8;
      float4 v = make_float4(0.f, 0.f, 0.f, 0.f);
      if (ok) v = ag4[c - 32];
      const int k = c * 4;
      xt[(k + 0) * ST3 + rl] = v.x;
      xt[(k + 1) * ST3 + rl] = v.y;
      xt[(k + 2) * ST3 + rl] = v.z;
      xt[(k + 3) * ST3 + rl] = v.w;
    }
  }
  __syncthreads();

  const int j4 = t & 31;
  const int e0 = (t >> 5) * 4;
  float4 acc[4];
  #pragma unroll
  for (int i = 0; i < 4; ++i) acc[i] = make_float4(0.f, 0.f, 0.f, 0.f);

  const float4* W4 = (const float4*)W_o;
  #pragma unroll 4
  for (int k = 0; k < 256; ++k) {
    const float4 w  = W4[k * 32 + j4];
    const float4 xa = *(const float4*)(xt + k * ST3 + e0);
    fma4(acc[0], w, xa.x); fma4(acc[1], w, xa.y);
    fma4(acc[2], w, xa.z); fma4(acc[3], w, xa.w);
  }

  const float4 b = ((const float4*)b_o)[j4];
  #pragma unroll
  for (int i = 0; i < 4; ++i) {
    const int gr = rbase + e0 + i;
    if (gr < NATOMS) {
      float4 r;
      r.x = fmaxf(acc[i].x + b.x, 0.f);
      r.y = fmaxf(acc[i].y + b.y, 0.f);
      r.z = fmaxf(acc[i].z + b.z, 0.f);
      r.w = fmaxf(acc[i].w + b.w, 0.f);
      *(float4*)(h_v_new + (long long)gr * HID + j4 * 4) = r;
    }
  }
}

// -----------------------------------------------------------------------------
extern "C" void kernel_launch(void* const* d_in, const int* in_sizes, int n_in,
                              void* d_out, int out_size, void* d_ws, size_t ws_size,
                              hipStream_t stream) {
  const float* h_v       = (const float*)d_in[0];
  const int*   ei        = (const int*)d_in[1];   // [2, NEDGES] int32 on device
  const float* edge_attr = (const float*)d_in[2];
  const float* h_e       = (const float*)d_in[3];
  const float* W_i       = (const float*)d_in[4];
  const float* W_h       = (const float*)d_in[5];
  const float* W_o       = (const float*)d_in[6];
  const float* b_o       = (const float*)d_in[7];
  const int*   dst       = ei + NEDGES;

  float* out       = (float*)d_out;
  float* agg       = out;                               // h_v_new region [20000,128]
  float* he_region = out + (size_t)NATOMS * HID;        // [640000,128] f32
  float* h_e_new   = he_region;

  // scratch inside the h_e_new region (consumed before k2 overwrites it):
  unsigned short* m = (unsigned short*)he_region;       // 640000*128 bf16 = 163.84 MB
  int* meta   = (int*)(he_region + (size_t)NEDGES * HID / 2);
  int* hist   = meta;                                   // 20000
  int* rowptr = meta + NATOMS;                          // 20001
  int* cursor = meta + 2 * NATOMS + 1;                  // 20000
  int* idx    = meta + 3 * NATOMS + 1;                  // 640000

  hipMemsetAsync(hist, 0, NATOMS * sizeof(int), stream);

  k_hist<<<(NEDGES + 255) / 256, 256, 0, stream>>>(dst, hist);
  k_scan<<<1, 256, 0, stream>>>(hist, rowptr, cursor);
  k_fill<<<(NEDGES + 255) / 256, 256, 0, stream>>>(dst, cursor, idx);

  k1_mfma<<<2500, 256, 0, stream>>>(h_v, ei, edge_attr, W_i, m);
  k_agg<<<NATOMS, 128, 0, stream>>>(m, rowptr, idx, agg);
  k2_mfma<<<2500, 256, 0, stream>>>(h_e, ei, W_h, agg, h_e_new);
  k3_atom_update<<<(NATOMS + 31) / 32, 256, 0, stream>>>(h_v, agg, W_o, b_o, agg);
}

// Round 5
// 452.774 us; speedup vs baseline: 3.2937x; 1.1435x over previous
//
#include <hip/hip_runtime.h>

#define NATOMS 20000
#define NEDGES 640000
#define HID 128
#define EDIM 64
#define NTILES (NEDGES / 64)   // 10000

typedef __attribute__((ext_vector_type(8))) short bf16x8;
typedef __attribute__((ext_vector_type(4))) float f32x4;

__device__ __forceinline__ unsigned short f2b(float f) {
  union { float f; unsigned u; } c; c.f = f;
  unsigned u = c.u + 0x7fff + ((c.u >> 16) & 1);   // RNE (finite data)
  return (unsigned short)(u >> 16);
}
__device__ __forceinline__ float b2f(unsigned short s) {
  union { unsigned u; float f; } c; c.u = ((unsigned)s) << 16;
  return c.f;
}

// pack 8 f32 -> 8 bf16 and write 16B to LDS
__device__ __forceinline__ void write8(unsigned short* p, float4 a, float4 b) {
  union { unsigned short u[8]; uint4 q; } pk;
  pk.u[0] = f2b(a.x); pk.u[1] = f2b(a.y); pk.u[2] = f2b(a.z); pk.u[3] = f2b(a.w);
  pk.u[4] = f2b(b.x); pk.u[5] = f2b(b.y); pk.u[6] = f2b(b.z); pk.u[7] = f2b(b.w);
  *(uint4*)p = pk.q;
}

// Per-wave W fragments: wave owns cols [wbase, wbase+32). W fp32 [K][128].
// b-frag lane l: B[k= ks*32 + (l>>4)*8 + j][ wbase + ni*16 + (l&15) ]
template <int KSTEPS>
__device__ __forceinline__ void load_w(const float* __restrict__ W, int wbase,
                                       int lane, bf16x8 B[KSTEPS][2]) {
  const int col0 = wbase + (lane & 15);
  const int krow0 = (lane >> 4) * 8;
  #pragma unroll
  for (int ks = 0; ks < KSTEPS; ++ks)
    #pragma unroll
    for (int ni = 0; ni < 2; ++ni) {
      const float* p = W + (long long)(ks * 32 + krow0) * HID + col0 + ni * 16;
      bf16x8 b;
      #pragma unroll
      for (int j = 0; j < 8; ++j) b[j] = (short)f2b(p[(long long)j * HID]);
      B[ks][ni] = b;
    }
}

// ---------------- CSR build --------------------------------------------------
__global__ __launch_bounds__(256) void k_hist(const int* __restrict__ dst,
                                              int* __restrict__ hist) {
  int e = blockIdx.x * 256 + threadIdx.x;
  if (e < NEDGES) atomicAdd(&hist[dst[e]], 1);
}

__global__ __launch_bounds__(256) void k_scan(const int* __restrict__ hist,
                                              int* __restrict__ rowptr,
                                              int* __restrict__ cursor) {
  __shared__ int part[256];
  const int t = threadIdx.x;
  const int CH = (NATOMS + 255) / 256;     // 79
  const int lo = t * CH, hi = min(lo + CH, NATOMS);
  int s = 0;
  for (int i = lo; i < hi; ++i) s += hist[i];
  part[t] = s; __syncthreads();
  for (int off = 1; off < 256; off <<= 1) {
    int v = (t >= off) ? part[t - off] : 0;
    __syncthreads();
    part[t] += v;
    __syncthreads();
  }
  int run = (t == 0) ? 0 : part[t - 1];
  for (int i = lo; i < hi; ++i) { rowptr[i] = run; cursor[i] = run; run += hist[i]; }
  if (t == 255) rowptr[NATOMS] = run;
}

__global__ __launch_bounds__(256) void k_fill(const int* __restrict__ dst,
                                              int* __restrict__ cursor,
                                              int* __restrict__ idx) {
  int e = blockIdx.x * 256 + threadIdx.x;
  if (e < NEDGES) {
    int p = atomicAdd(&cursor[dst[e]], 1);
    idx[p] = e;
  }
}

// ---- K1 fused: per sorted-edge tile, m = relu([h_v[src]|ea] @ W_i) in LDS,
//      then per-column segment-sum over the tile -> few atomics into agg. ----
#define A1_ST 200   // bf16 staging row stride (mult of 8 -> 16B aligned)
#define M_ST  132   // f32 m-tile row stride (pad 4 -> spread banks)

__global__ __launch_bounds__(256, 2) void k1_fused(
    const float* __restrict__ h_v, const int* __restrict__ ei,
    const float* __restrict__ edge_attr, const float* __restrict__ W_i,
    const int* __restrict__ idx, float* __restrict__ agg)
{
  // overlay: bf16 A-staging (25.6 KB) then f32 m-tile (33.8 KB)
  __shared__ __align__(16) char smem[64 * M_ST * 4];
  unsigned short* A = (unsigned short*)smem;
  float* M = (float*)smem;
  __shared__ int dstl[64];

  const int t = threadIdx.x, lane = t & 63, w = t >> 6;

  bf16x8 B[6][2];
  load_w<6>(W_i, w * 32, lane, B);

  for (int tile = blockIdx.x; tile < NTILES; tile += gridDim.x) {
    const int ebase = tile * 64;
    const int e = idx[ebase + lane];         // dst-sorted edge id
    { // stage A: wave w covers cols [w*48, w*48+48); lane = tile row
      const int s = ei[e];                   // src atom
      if (w == 0) dstl[lane] = ei[NEDGES + e];
      const float* hv = h_v + (long long)s * HID;
      const float* ea = edge_attr + (long long)e * EDIM;
      #pragma unroll
      for (int i = 0; i < 6; ++i) {
        const int c0 = w * 48 + i * 8;
        const float* src = (c0 < HID) ? (hv + c0) : (ea + (c0 - HID));
        float4 v0 = *(const float4*)(src);
        float4 v1 = *(const float4*)(src + 4);
        write8(&A[lane * A1_ST + c0], v0, v1);
      }
    }
    __syncthreads();

    f32x4 acc[4][2];
    #pragma unroll
    for (int mi = 0; mi < 4; ++mi)
      #pragma unroll
      for (int ni = 0; ni < 2; ++ni) acc[mi][ni] = (f32x4){0.f, 0.f, 0.f, 0.f};

    #pragma unroll
    for (int ks = 0; ks < 6; ++ks) {
      const int kk = ks * 32 + (lane >> 4) * 8;
      bf16x8 a[4];
      #pragma unroll
      for (int mi = 0; mi < 4; ++mi)
        a[mi] = *(const bf16x8*)&A[(mi * 16 + (lane & 15)) * A1_ST + kk];
      #pragma unroll
      for (int mi = 0; mi < 4; ++mi) {
        acc[mi][0] = __builtin_amdgcn_mfma_f32_16x16x32_bf16(a[mi], B[ks][0], acc[mi][0], 0, 0, 0);
        acc[mi][1] = __builtin_amdgcn_mfma_f32_16x16x32_bf16(a[mi], B[ks][1], acc[mi][1], 0, 0, 0);
      }
    }
    __syncthreads();   // all A reads done before M overwrites the same bytes

    { // relu -> f32 m-tile in LDS.  D: col=lane&15, row=(lane>>4)*4+reg
      const int colb = w * 32 + (lane & 15);
      const int r0 = (lane >> 4) << 2;
      #pragma unroll
      for (int mi = 0; mi < 4; ++mi)
        #pragma unroll
        for (int ni = 0; ni < 2; ++ni)
          #pragma unroll
          for (int r = 0; r < 4; ++r)
            M[(mi * 16 + r0 + r) * M_ST + colb + ni * 16] =
                fmaxf(acc[mi][ni][r], 0.f);
    }
    __syncthreads();

    { // segment-sum: 2 threads/col, 32 rows each; dst runs are contiguous.
      const int j = t & 127, h = t >> 7;
      const int r0 = h * 32;
      int cur = dstl[r0];
      float s = 0.f;
      #pragma unroll 4
      for (int r = r0; r < r0 + 32; ++r) {
        const int d = dstl[r];               // wave-uniform -> scalar branch
        if (d != cur) {
          atomicAdd(&agg[(long long)cur * HID + j], s);
          s = 0.f; cur = d;
        }
        s += M[r * M_ST + j];
      }
      atomicAdd(&agg[(long long)cur * HID + j], s);
    }
    __syncthreads();
  }
}

// ---------------- K2: h_e_new = relu(h_e @ W_h + agg[src])  (bf16 MFMA) ------
#define A2_ST 136   // mult of 8 -> aligned; 2-way banks

__global__ __launch_bounds__(256, 2) void k2_mfma(
    const float* __restrict__ h_e, const int* __restrict__ ei,
    const float* __restrict__ W_h, const float* __restrict__ agg,
    float* __restrict__ h_e_new)
{
  __shared__ __align__(16) unsigned short A[64 * A2_ST];   // 17.4 KB
  const int t = threadIdx.x, lane = t & 63, w = t >> 6;

  bf16x8 B[4][2];
  load_w<4>(W_h, w * 32, lane, B);

  for (int tile = blockIdx.x; tile < NTILES; tile += gridDim.x) {
    const int ebase = tile * 64;
    { // stage h_e rows (sequential)
      const float* he = h_e + (long long)(ebase + lane) * HID;
      #pragma unroll
      for (int i = 0; i < 4; ++i) {
        const int c0 = w * 32 + i * 8;
        float4 v0 = *(const float4*)(he + c0);
        float4 v1 = *(const float4*)(he + c0 + 4);
        write8(&A[lane * A2_ST + c0], v0, v1);
      }
    }
    __syncthreads();

    f32x4 acc[4][2];
    #pragma unroll
    for (int mi = 0; mi < 4; ++mi)
      #pragma unroll
      for (int ni = 0; ni < 2; ++ni) acc[mi][ni] = (f32x4){0.f, 0.f, 0.f, 0.f};

    #pragma unroll
    for (int ks = 0; ks < 4; ++ks) {
      const int kk = ks * 32 + (lane >> 4) * 8;
      bf16x8 a[4];
      #pragma unroll
      for (int mi = 0; mi < 4; ++mi)
        a[mi] = *(const bf16x8*)&A[(mi * 16 + (lane & 15)) * A2_ST + kk];
      #pragma unroll
      for (int mi = 0; mi < 4; ++mi) {
        acc[mi][0] = __builtin_amdgcn_mfma_f32_16x16x32_bf16(a[mi], B[ks][0], acc[mi][0], 0, 0, 0);
        acc[mi][1] = __builtin_amdgcn_mfma_f32_16x16x32_bf16(a[mi], B[ks][1], acc[mi][1], 0, 0, 0);
      }
    }

    { // epilogue: + agg[src] gather, relu, f32 stores
      const int colb = w * 32 + (lane & 15);
      const int rb = ebase + ((lane >> 4) << 2);
      #pragma unroll
      for (int mi = 0; mi < 4; ++mi)
        #pragma unroll
        for (int r = 0; r < 4; ++r) {
          const int row = rb + mi * 16 + r;
          const int s = ei[row];                    // src
          const float* ag = agg + (long long)s * HID + colb;
          float* o = h_e_new + (long long)row * HID + colb;
          o[0]  = fmaxf(acc[mi][0][r] + ag[0], 0.f);
          o[16] = fmaxf(acc[mi][1][r] + ag[16], 0.f);
        }
    }
    __syncthreads();
  }
}

// ---------------- K3: h_v_new = relu([h_v, agg] @ W_o + b_o)  (fp32 VALU) ----
// h_v_new aliases agg (in-place); each block stages its 32 rows before sync.
__device__ __forceinline__ void fma4(float4& a, const float4 w, const float s) {
  a.x = fmaf(w.x, s, a.x);
  a.y = fmaf(w.y, s, a.y);
  a.z = fmaf(w.z, s, a.z);
  a.w = fmaf(w.w, s, a.w);
}
#define ST3 36

__global__ __launch_bounds__(256) void k3_atom_update(
    const float* __restrict__ h_v, const float* __restrict__ agg,
    const float* __restrict__ W_o, const float* __restrict__ b_o,
    float* __restrict__ h_v_new)
{
  __shared__ float xt[256 * ST3];
  const int t = threadIdx.x;
  const int rbase = blockIdx.x * 32;

  {
    const int rl = t & 31;
    const int part = t >> 5;
    const int gr = rbase + rl;
    const bool ok = gr < NATOMS;
    const float4* hv4 = (const float4*)(h_v + (long long)gr * HID);
    const float4* ag4 = (const float4*)(agg + (long long)gr * HID);
    #pragma unroll
    for (int i = 0; i < 4; ++i) {
      const int c = part + i * 8;
      float4 v = make_float4(0.f, 0.f, 0.f, 0.f);
      if (ok) v = hv4[c];
      const int k = c * 4;
      xt[(k + 0) * ST3 + rl] = v.x;
      xt[(k + 1) * ST3 + rl] = v.y;
      xt[(k + 2) * ST3 + rl] = v.z;
      xt[(k + 3) * ST3 + rl] = v.w;
    }
    #pragma unroll
    for (int i = 4; i < 8; ++i) {
      const int c = part + i * 8;
      float4 v = make_float4(0.f, 0.f, 0.f, 0.f);
      if (ok) v = ag4[c - 32];
      const int k = c * 4;
      xt[(k + 0) * ST3 + rl] = v.x;
      xt[(k + 1) * ST3 + rl] = v.y;
      xt[(k + 2) * ST3 + rl] = v.z;
      xt[(k + 3) * ST3 + rl] = v.w;
    }
  }
  __syncthreads();

  const int j4 = t & 31;
  const int e0 = (t >> 5) * 4;
  float4 acc[4];
  #pragma unroll
  for (int i = 0; i < 4; ++i) acc[i] = make_float4(0.f, 0.f, 0.f, 0.f);

  const float4* W4 = (const float4*)W_o;
  #pragma unroll 4
  for (int k = 0; k < 256; ++k) {
    const float4 w  = W4[k * 32 + j4];
    const float4 xa = *(const float4*)(xt + k * ST3 + e0);
    fma4(acc[0], w, xa.x); fma4(acc[1], w, xa.y);
    fma4(acc[2], w, xa.z); fma4(acc[3], w, xa.w);
  }

  const float4 b = ((const float4*)b_o)[j4];
  #pragma unroll
  for (int i = 0; i < 4; ++i) {
    const int gr = rbase + e0 + i;
    if (gr < NATOMS) {
      float4 r;
      r.x = fmaxf(acc[i].x + b.x, 0.f);
      r.y = fmaxf(acc[i].y + b.y, 0.f);
      r.z = fmaxf(acc[i].z + b.z, 0.f);
      r.w = fmaxf(acc[i].w + b.w, 0.f);
      *(float4*)(h_v_new + (long long)gr * HID + j4 * 4) = r;
    }
  }
}

// -----------------------------------------------------------------------------
extern "C" void kernel_launch(void* const* d_in, const int* in_sizes, int n_in,
                              void* d_out, int out_size, void* d_ws, size_t ws_size,
                              hipStream_t stream) {
  const float* h_v       = (const float*)d_in[0];
  const int*   ei        = (const int*)d_in[1];   // [2, NEDGES] int32 on device
  const float* edge_attr = (const float*)d_in[2];
  const float* h_e       = (const float*)d_in[3];
  const float* W_i       = (const float*)d_in[4];
  const float* W_h       = (const float*)d_in[5];
  const float* W_o       = (const float*)d_in[6];
  const float* b_o       = (const float*)d_in[7];
  const int*   dst       = ei + NEDGES;

  float* out       = (float*)d_out;
  float* agg       = out;                               // h_v_new region [20000,128]
  float* he_region = out + (size_t)NATOMS * HID;        // [640000,128] f32
  float* h_e_new   = he_region;

  // CSR scratch inside the h_e_new region (only read by k1; k2 overwrites later)
  int* meta   = (int*)he_region;
  int* hist   = meta;                                   // 20000
  int* rowptr = meta + NATOMS;                          // 20001
  int* cursor = meta + 2 * NATOMS + 1;                  // 20000
  int* idx    = meta + 3 * NATOMS + 1;                  // 640000

  hipMemsetAsync(hist, 0, NATOMS * sizeof(int), stream);
  hipMemsetAsync(agg, 0, (size_t)NATOMS * HID * sizeof(float), stream);

  k_hist<<<(NEDGES + 255) / 256, 256, 0, stream>>>(dst, hist);
  k_scan<<<1, 256, 0, stream>>>(hist, rowptr, cursor);
  k_fill<<<(NEDGES + 255) / 256, 256, 0, stream>>>(dst, cursor, idx);

  k1_fused<<<2500, 256, 0, stream>>>(h_v, ei, edge_attr, W_i, idx, agg);
  k2_mfma<<<2500, 256, 0, stream>>>(h_e, ei, W_h, agg, h_e_new);
  k3_atom_update<<<(NATOMS + 31) / 32, 256, 0, stream>>>(h_v, agg, W_o, b_o, agg);
}

// Round 6
// 444.501 us; speedup vs baseline: 3.3551x; 1.0186x over previous
//
#include <hip/hip_runtime.h>
#include <hip/hip_bf16.h>

#define NATOMS 20000
#define NEDGES 640000
#define HID 128
#define EDIM 64
#define NTILES (NEDGES / 64)   // 10000

typedef __attribute__((ext_vector_type(8))) short bf16x8;
typedef __attribute__((ext_vector_type(4))) float f32x4;

__device__ __forceinline__ unsigned short f2b(float f) {
  union { float f; unsigned u; } c; c.f = f;
  unsigned u = c.u + 0x7fff + ((c.u >> 16) & 1);   // RNE (finite data)
  return (unsigned short)(u >> 16);
}

// pack 8 f32 -> 8 bf16 (HW v_cvt_pk_bf16_f32) and write 16B to LDS
__device__ __forceinline__ void write8(unsigned short* p, float4 a, float4 b) {
  union { __hip_bfloat162 h[4]; uint4 q; } pk;
  pk.h[0] = __float22bfloat162_rn(make_float2(a.x, a.y));
  pk.h[1] = __float22bfloat162_rn(make_float2(a.z, a.w));
  pk.h[2] = __float22bfloat162_rn(make_float2(b.x, b.y));
  pk.h[3] = __float22bfloat162_rn(make_float2(b.z, b.w));
  *(uint4*)p = pk.q;
}

// Per-wave W fragments: wave owns cols [wbase, wbase+32). W fp32 [K][128].
// b-frag lane l: B[k= ks*32 + (l>>4)*8 + j][ wbase + ni*16 + (l&15) ]
template <int KSTEPS>
__device__ __forceinline__ void load_w(const float* __restrict__ W, int wbase,
                                       int lane, bf16x8 B[KSTEPS][2]) {
  const int col0 = wbase + (lane & 15);
  const int krow0 = (lane >> 4) * 8;
  #pragma unroll
  for (int ks = 0; ks < KSTEPS; ++ks)
    #pragma unroll
    for (int ni = 0; ni < 2; ++ni) {
      const float* p = W + (long long)(ks * 32 + krow0) * HID + col0 + ni * 16;
      bf16x8 b;
      #pragma unroll
      for (int j = 0; j < 8; ++j) b[j] = (short)f2b(p[(long long)j * HID]);
      B[ks][ni] = b;
    }
}

// ---------------- CSR build --------------------------------------------------
__global__ __launch_bounds__(256) void k_hist(const int* __restrict__ dst,
                                              int* __restrict__ hist) {
  int e = blockIdx.x * 256 + threadIdx.x;
  if (e < NEDGES) atomicAdd(&hist[dst[e]], 1);
}

__global__ __launch_bounds__(256) void k_scan(const int* __restrict__ hist,
                                              int* __restrict__ rowptr,
                                              int* __restrict__ cursor) {
  __shared__ int part[256];
  const int t = threadIdx.x;
  const int CH = (NATOMS + 255) / 256;     // 79
  const int lo = t * CH, hi = min(lo + CH, NATOMS);
  int s = 0;
  for (int i = lo; i < hi; ++i) s += hist[i];
  part[t] = s; __syncthreads();
  for (int off = 1; off < 256; off <<= 1) {
    int v = (t >= off) ? part[t - off] : 0;
    __syncthreads();
    part[t] += v;
    __syncthreads();
  }
  int run = (t == 0) ? 0 : part[t - 1];
  for (int i = lo; i < hi; ++i) { rowptr[i] = run; cursor[i] = run; run += hist[i]; }
  if (t == 255) rowptr[NATOMS] = run;
}

__global__ __launch_bounds__(256) void k_fill(const int* __restrict__ dst,
                                              int* __restrict__ cursor,
                                              int* __restrict__ idx) {
  int e = blockIdx.x * 256 + threadIdx.x;
  if (e < NEDGES) {
    int p = atomicAdd(&cursor[dst[e]], 1);
    idx[p] = e;
  }
}

// ---- K1 fused: per sorted-edge tile, m = relu([h_v[src]|ea] @ W_i) in LDS,
//      then per-column segment-sum over the tile -> few atomics into agg. ----
#define A1_ST 200   // bf16 staging row stride (mult of 8 -> 16B aligned)
#define M_ST  132   // f32 m-tile row stride (pad 4 -> spread banks)

__global__ __launch_bounds__(256, 2) void k1_fused(
    const float* __restrict__ h_v, const int* __restrict__ ei,
    const float* __restrict__ edge_attr, const float* __restrict__ W_i,
    const int* __restrict__ idx, float* __restrict__ agg)
{
  // overlay: bf16 A-staging (25.6 KB) then f32 m-tile (33.8 KB)
  __shared__ __align__(16) char smem[64 * M_ST * 4];
  unsigned short* A = (unsigned short*)smem;
  float* M = (float*)smem;
  __shared__ int dstl[64];

  const int t = threadIdx.x, lane = t & 63, w = t >> 6;

  bf16x8 B[6][2];
  load_w<6>(W_i, w * 32, lane, B);

  for (int tile = blockIdx.x; tile < NTILES; tile += gridDim.x) {
    const int ebase = tile * 64;
    const int e = idx[ebase + lane];         // dst-sorted edge id
    { // stage A: wave w covers cols [w*48, w*48+48); lane = tile row
      const int s = ei[e];                   // src atom
      if (w == 0) dstl[lane] = ei[NEDGES + e];
      const float* hv = h_v + (long long)s * HID;
      const float* ea = edge_attr + (long long)e * EDIM;
      #pragma unroll
      for (int i = 0; i < 6; ++i) {
        const int c0 = w * 48 + i * 8;
        const float* src = (c0 < HID) ? (hv + c0) : (ea + (c0 - HID));
        float4 v0 = *(const float4*)(src);
        float4 v1 = *(const float4*)(src + 4);
        write8(&A[lane * A1_ST + c0], v0, v1);
      }
    }
    __syncthreads();

    f32x4 acc[4][2];
    #pragma unroll
    for (int mi = 0; mi < 4; ++mi)
      #pragma unroll
      for (int ni = 0; ni < 2; ++ni) acc[mi][ni] = (f32x4){0.f, 0.f, 0.f, 0.f};

    #pragma unroll
    for (int ks = 0; ks < 6; ++ks) {
      const int kk = ks * 32 + (lane >> 4) * 8;
      bf16x8 a[4];
      #pragma unroll
      for (int mi = 0; mi < 4; ++mi)
        a[mi] = *(const bf16x8*)&A[(mi * 16 + (lane & 15)) * A1_ST + kk];
      #pragma unroll
      for (int mi = 0; mi < 4; ++mi) {
        acc[mi][0] = __builtin_amdgcn_mfma_f32_16x16x32_bf16(a[mi], B[ks][0], acc[mi][0], 0, 0, 0);
        acc[mi][1] = __builtin_amdgcn_mfma_f32_16x16x32_bf16(a[mi], B[ks][1], acc[mi][1], 0, 0, 0);
      }
    }
    __syncthreads();   // all A reads done before M overwrites the same bytes

    { // relu -> f32 m-tile in LDS.  D: col=lane&15, row=(lane>>4)*4+reg
      const int colb = w * 32 + (lane & 15);
      const int r0 = (lane >> 4) << 2;
      #pragma unroll
      for (int mi = 0; mi < 4; ++mi)
        #pragma unroll
        for (int ni = 0; ni < 2; ++ni)
          #pragma unroll
          for (int r = 0; r < 4; ++r)
            M[(mi * 16 + r0 + r) * M_ST + colb + ni * 16] =
                fmaxf(acc[mi][ni][r], 0.f);
    }
    __syncthreads();

    { // segment-sum: 2 threads/col, 32 rows each; dst runs are contiguous.
      const int j = t & 127, h = t >> 7;
      const int r0 = h * 32;
      int cur = dstl[r0];
      float s = 0.f;
      #pragma unroll 4
      for (int r = r0; r < r0 + 32; ++r) {
        const int d = dstl[r];               // wave-uniform -> scalar branch
        if (d != cur) {
          atomicAdd(&agg[(long long)cur * HID + j], s);
          s = 0.f; cur = d;
        }
        s += M[r * M_ST + j];
      }
      atomicAdd(&agg[(long long)cur * HID + j], s);
    }
    __syncthreads();
  }
}

// ---------------- K2: h_e_new = relu(h_e @ W_h + agg[src])  (bf16 MFMA) ------
// Epilogue routes acc through an LDS f32 tile so agg-gather and stores are
// float4/row-contiguous (cuts ~80 scalar VMEM ops/lane/tile to ~32 vector).
#define A2_ST 136   // bf16 staging stride (mult of 8 -> aligned)
#define M2_ST 132   // f32 out-tile stride

__global__ __launch_bounds__(256, 2) void k2_mfma(
    const float* __restrict__ h_e, const int* __restrict__ ei,
    const float* __restrict__ W_h, const float* __restrict__ agg,
    float* __restrict__ h_e_new)
{
  // overlay: bf16 A-staging (17.4 KB) then f32 out-tile (33.8 KB)
  __shared__ __align__(16) char smem[64 * M2_ST * 4];
  unsigned short* A = (unsigned short*)smem;
  float* M = (float*)smem;

  const int t = threadIdx.x, lane = t & 63, w = t >> 6;

  bf16x8 B[4][2];
  load_w<4>(W_h, w * 32, lane, B);

  for (int tile = blockIdx.x; tile < NTILES; tile += gridDim.x) {
    const int ebase = tile * 64;
    { // stage h_e rows (sequential)
      const float* he = h_e + (long long)(ebase + lane) * HID;
      #pragma unroll
      for (int i = 0; i < 4; ++i) {
        const int c0 = w * 32 + i * 8;
        float4 v0 = *(const float4*)(he + c0);
        float4 v1 = *(const float4*)(he + c0 + 4);
        write8(&A[lane * A2_ST + c0], v0, v1);
      }
    }
    __syncthreads();

    f32x4 acc[4][2];
    #pragma unroll
    for (int mi = 0; mi < 4; ++mi)
      #pragma unroll
      for (int ni = 0; ni < 2; ++ni) acc[mi][ni] = (f32x4){0.f, 0.f, 0.f, 0.f};

    #pragma unroll
    for (int ks = 0; ks < 4; ++ks) {
      const int kk = ks * 32 + (lane >> 4) * 8;
      bf16x8 a[4];
      #pragma unroll
      for (int mi = 0; mi < 4; ++mi)
        a[mi] = *(const bf16x8*)&A[(mi * 16 + (lane & 15)) * A2_ST + kk];
      #pragma unroll
      for (int mi = 0; mi < 4; ++mi) {
        acc[mi][0] = __builtin_amdgcn_mfma_f32_16x16x32_bf16(a[mi], B[ks][0], acc[mi][0], 0, 0, 0);
        acc[mi][1] = __builtin_amdgcn_mfma_f32_16x16x32_bf16(a[mi], B[ks][1], acc[mi][1], 0, 0, 0);
      }
    }
    __syncthreads();   // all A reads done before M overwrites the same bytes

    { // acc -> f32 LDS tile (no relu yet; agg added in epilogue)
      const int colb = w * 32 + (lane & 15);
      const int r0 = (lane >> 4) << 2;
      #pragma unroll
      for (int mi = 0; mi < 4; ++mi)
        #pragma unroll
        for (int ni = 0; ni < 2; ++ni)
          #pragma unroll
          for (int r = 0; r < 4; ++r)
            M[(mi * 16 + r0 + r) * M2_ST + colb + ni * 16] = acc[mi][ni][r];
    }
    __syncthreads();

    { // vectorized epilogue: lanes 0-31 cover one row's 128 cols as float4s
      const int quad = t & 31;             // col quad
      const int rb = t >> 5;               // 0..7
      #pragma unroll
      for (int it = 0; it < 8; ++it) {
        const int row = rb + it * 8;
        const int grow = ebase + row;
        const int s = ei[grow];            // src
        const float4 mm = *(const float4*)&M[row * M2_ST + quad * 4];
        const float4 ag = *(const float4*)(agg + (long long)s * HID + quad * 4);
        float4 r;
        r.x = fmaxf(mm.x + ag.x, 0.f);
        r.y = fmaxf(mm.y + ag.y, 0.f);
        r.z = fmaxf(mm.z + ag.z, 0.f);
        r.w = fmaxf(mm.w + ag.w, 0.f);
        *(float4*)(h_e_new + (long long)grow * HID + quad * 4) = r;
      }
    }
    __syncthreads();
  }
}

// ---------------- K3: h_v_new = relu([h_v, agg] @ W_o + b_o)  (fp32 VALU) ----
// h_v_new aliases agg (in-place); each block stages its 32 rows before sync.
__device__ __forceinline__ void fma4(float4& a, const float4 w, const float s) {
  a.x = fmaf(w.x, s, a.x);
  a.y = fmaf(w.y, s, a.y);
  a.z = fmaf(w.z, s, a.z);
  a.w = fmaf(w.w, s, a.w);
}
#define ST3 36

__global__ __launch_bounds__(256) void k3_atom_update(
    const float* __restrict__ h_v, const float* __restrict__ agg,
    const float* __restrict__ W_o, const float* __restrict__ b_o,
    float* __restrict__ h_v_new)
{
  __shared__ float xt[256 * ST3];
  const int t = threadIdx.x;
  const int rbase = blockIdx.x * 32;

  {
    const int rl = t & 31;
    const int part = t >> 5;
    const int gr = rbase + rl;
    const bool ok = gr < NATOMS;
    const float4* hv4 = (const float4*)(h_v + (long long)gr * HID);
    const float4* ag4 = (const float4*)(agg + (long long)gr * HID);
    #pragma unroll
    for (int i = 0; i < 4; ++i) {
      const int c = part + i * 8;
      float4 v = make_float4(0.f, 0.f, 0.f, 0.f);
      if (ok) v = hv4[c];
      const int k = c * 4;
      xt[(k + 0) * ST3 + rl] = v.x;
      xt[(k + 1) * ST3 + rl] = v.y;
      xt[(k + 2) * ST3 + rl] = v.z;
      xt[(k + 3) * ST3 + rl] = v.w;
    }
    #pragma unroll
    for (int i = 4; i < 8; ++i) {
      const int c = part + i * 8;
      float4 v = make_float4(0.f, 0.f, 0.f, 0.f);
      if (ok) v = ag4[c - 32];
      const int k = c * 4;
      xt[(k + 0) * ST3 + rl] = v.x;
      xt[(k + 1) * ST3 + rl] = v.y;
      xt[(k + 2) * ST3 + rl] = v.z;
      xt[(k + 3) * ST3 + rl] = v.w;
    }
  }
  __syncthreads();

  const int j4 = t & 31;
  const int e0 = (t >> 5) * 4;
  float4 acc[4];
  #pragma unroll
  for (int i = 0; i < 4; ++i) acc[i] = make_float4(0.f, 0.f, 0.f, 0.f);

  const float4* W4 = (const float4*)W_o;
  #pragma unroll 4
  for (int k = 0; k < 256; ++k) {
    const float4 w  = W4[k * 32 + j4];
    const float4 xa = *(const float4*)(xt + k * ST3 + e0);
    fma4(acc[0], w, xa.x); fma4(acc[1], w, xa.y);
    fma4(acc[2], w, xa.z); fma4(acc[3], w, xa.w);
  }

  const float4 b = ((const float4*)b_o)[j4];
  #pragma unroll
  for (int i = 0; i < 4; ++i) {
    const int gr = rbase + e0 + i;
    if (gr < NATOMS) {
      float4 r;
      r.x = fmaxf(acc[i].x + b.x, 0.f);
      r.y = fmaxf(acc[i].y + b.y, 0.f);
      r.z = fmaxf(acc[i].z + b.z, 0.f);
      r.w = fmaxf(acc[i].w + b.w, 0.f);
      *(float4*)(h_v_new + (long long)gr * HID + j4 * 4) = r;
    }
  }
}

// -----------------------------------------------------------------------------
extern "C" void kernel_launch(void* const* d_in, const int* in_sizes, int n_in,
                              void* d_out, int out_size, void* d_ws, size_t ws_size,
                              hipStream_t stream) {
  const float* h_v       = (const float*)d_in[0];
  const int*   ei        = (const int*)d_in[1];   // [2, NEDGES] int32 on device
  const float* edge_attr = (const float*)d_in[2];
  const float* h_e       = (const float*)d_in[3];
  const float* W_i       = (const float*)d_in[4];
  const float* W_h       = (const float*)d_in[5];
  const float* W_o       = (const float*)d_in[6];
  const float* b_o       = (const float*)d_in[7];
  const int*   dst       = ei + NEDGES;

  float* out       = (float*)d_out;
  float* agg       = out;                               // h_v_new region [20000,128]
  float* he_region = out + (size_t)NATOMS * HID;        // [640000,128] f32
  float* h_e_new   = he_region;

  // CSR scratch inside the h_e_new region (only read by k1; k2 overwrites later)
  int* meta   = (int*)he_region;
  int* hist   = meta;                                   // 20000
  int* rowptr = meta + NATOMS;                          // 20001
  int* cursor = meta + 2 * NATOMS + 1;                  // 20000
  int* idx    = meta + 3 * NATOMS + 1;                  // 640000

  hipMemsetAsync(hist, 0, NATOMS * sizeof(int), stream);
  hipMemsetAsync(agg, 0, (size_t)NATOMS * HID * sizeof(float), stream);

  k_hist<<<(NEDGES + 255) / 256, 256, 0, stream>>>(dst, hist);
  k_scan<<<1, 256, 0, stream>>>(hist, rowptr, cursor);
  k_fill<<<(NEDGES + 255) / 256, 256, 0, stream>>>(dst, cursor, idx);

  k1_fused<<<2500, 256, 0, stream>>>(h_v, ei, edge_attr, W_i, idx, agg);
  k2_mfma<<<2500, 256, 0, stream>>>(h_e, ei, W_h, agg, h_e_new);
  k3_atom_update<<<(NATOMS + 31) / 32, 256, 0, stream>>>(h_v, agg, W_o, b_o, agg);
}